// Round 14
// baseline (125.383 us; speedup 1.0000x reference)
//
#include <hip/hip_runtime.h>
#include <hip/hip_bf16.h>
#include <math.h>

#define SEQ 2048
#define NH  16
#define DKH 64
#define DM  1024
#define MR  4096   // BATCH*SEQ

using bf16x8 = __attribute__((ext_vector_type(8))) short;
using f32x4  = __attribute__((ext_vector_type(4))) float;

__device__ __forceinline__ ushort f2b(float f) {
  unsigned u = __float_as_uint(f);
  return (ushort)((u + 0x7fffu + ((u >> 16) & 1u)) >> 16);
}

__device__ __forceinline__ float exp2_fast(float x) {
  float r; asm("v_exp_f32 %0, %1" : "=v"(r) : "v"(x)); return r;
}

// packed bf16 pair via compiler intrinsic (correct hazards/scheduling)
__device__ __forceinline__ unsigned cvt_pk(float lo, float hi) {
  __hip_bfloat162 h = __float22bfloat162_rn(float2{lo, hi});
  return *reinterpret_cast<unsigned*>(&h);
}

__device__ __forceinline__ void gll16(const void* g, void* l) {
  __builtin_amdgcn_global_load_lds(
      (const __attribute__((address_space(1))) void*)g,
      (__attribute__((address_space(3))) void*)l, 16, 0, 0);
}

// ---------------------------------------------------------------------------
// fp32 -> bf16 conversion of x and the 4 weight matrices (one launch)
// ---------------------------------------------------------------------------
__global__ __launch_bounds__(256) void cvt_all(
    const float* __restrict__ x,  const float* __restrict__ wq,
    const float* __restrict__ wk, const float* __restrict__ wv,
    const float* __restrict__ wo,
    ushort* __restrict__ xb,  ushort* __restrict__ wqb, ushort* __restrict__ wkb,
    ushort* __restrict__ wvb, ushort* __restrict__ wob)
{
  size_t e = ((size_t)blockIdx.x * 256 + threadIdx.x) * 4;
  const float* s; ushort* d; size_t off;
  if      (e < 4194304) { s = x;  d = xb;  off = e; }
  else if (e < 5242880) { s = wq; d = wqb; off = e - 4194304; }
  else if (e < 6291456) { s = wk; d = wkb; off = e - 5242880; }
  else if (e < 7340032) { s = wv; d = wvb; off = e - 6291456; }
  else                  { s = wo; d = wob; off = e - 7340032; }
  float4 f = *(const float4*)(s + off);
  ushort4 o4 = { f2b(f.x), f2b(f.y), f2b(f.z), f2b(f.w) };
  *(ushort4*)(d + off) = o4;
}

// ---------------------------------------------------------------------------
// Fused QKV projection (unchanged; Q pre-scale 0.125*log2(e)).
// ---------------------------------------------------------------------------
__global__ __launch_bounds__(512) void gemm_qkv(
    const ushort* __restrict__ X,
    const ushort* __restrict__ Wq, const ushort* __restrict__ Wk, const ushort* __restrict__ Wv,
    ushort* __restrict__ Q, ushort* __restrict__ K, ushort* __restrict__ Vt,
    const int* __restrict__ pos)
{
  __shared__ __align__(16) char As[2][16384];
  __shared__ __align__(16) char Bs[2][16384];

  const int id  = blockIdx.x;          // 768 blocks
  const int xcd = id & 7;
  const int i   = id >> 3;             // 0..95
  const int mt  = xcd * 4 + (i & 3);   // 0..31
  const int nt  = i >> 2;              // 0..23
  const int m0  = mt * 128;
  const int nG  = nt * 128;
  const int z   = nG >> 10;            // 0:Q 1:K 2:V
  const int n0  = nG & 1023;
  const ushort* W = (z == 0) ? Wq : (z == 1) ? Wk : Wv;

  const int tid  = threadIdx.x;
  const int lane = tid & 63;
  const int w    = tid >> 6;           // 0..7
  const int wm   = (w >> 2) * 64;
  const int wn   = (w & 3) * 32;
  const int li   = lane & 15;
  const int g    = lane >> 4;

  f32x4 acc[4][2] = {};

  auto stage = [&](int t, int buf) {
    const int k0 = t * 64;
    #pragma unroll
    for (int it = 0; it < 2; ++it) {
      const int L  = w * 2048 + it * 1024 + lane * 16;
      const int r  = L >> 7;
      const int sc = ((L >> 4) & 7) ^ (r & 7);
      gll16(X + (size_t)(m0 + r) * DM + k0 + sc * 8, &As[buf][w * 2048 + it * 1024]);
      gll16(W + (size_t)(n0 + r) * DM + k0 + sc * 8, &Bs[buf][w * 2048 + it * 1024]);
    }
  };

  auto compute = [&](int buf) {
    #pragma unroll
    for (int ks = 0; ks < 2; ++ks) {
      bf16x8 af[4], bfr[2];
      #pragma unroll
      for (int mf = 0; mf < 4; ++mf) {
        const int row = wm + mf * 16 + li;
        af[mf] = *(const bf16x8*)(&As[buf][row * 128 + (((ks * 4 + g) ^ (row & 7)) << 4)]);
      }
      #pragma unroll
      for (int nf = 0; nf < 2; ++nf) {
        const int row = wn + nf * 16 + li;
        bfr[nf] = *(const bf16x8*)(&Bs[buf][row * 128 + (((ks * 4 + g) ^ (row & 7)) << 4)]);
      }
      #pragma unroll
      for (int mf = 0; mf < 4; ++mf)
        #pragma unroll
        for (int nf = 0; nf < 2; ++nf)
          acc[mf][nf] = __builtin_amdgcn_mfma_f32_16x16x32_bf16(af[mf], bfr[nf], acc[mf][nf], 0, 0, 0);
    }
  };

  stage(0, 0);
  for (int t = 0; t < 16; ++t) {
    if (t < 15) {
      stage(t + 1, (t + 1) & 1);
      __builtin_amdgcn_sched_barrier(0);
      asm volatile("s_waitcnt vmcnt(4)" ::: "memory");
    } else {
      asm volatile("s_waitcnt vmcnt(0)" ::: "memory");
    }
    __builtin_amdgcn_s_barrier();
    __builtin_amdgcn_sched_barrier(0);
    compute(t & 1);
    __builtin_amdgcn_sched_barrier(0);
    __builtin_amdgcn_s_barrier();
  }

  #pragma unroll
  for (int nf = 0; nf < 2; ++nf) {
    const int n = n0 + wn + nf * 16 + li;
    const int h = n >> 6;
    const int d = n & 63;
    if (z == 2) {
      #pragma unroll
      for (int mf = 0; mf < 4; ++mf) {
        const int m  = m0 + wm + mf * 16 + g * 4;
        const int b  = m >> 11;
        const int s2 = m & (SEQ - 1);
        ushort4 pk = { f2b(acc[mf][nf][0]), f2b(acc[mf][nf][1]),
                       f2b(acc[mf][nf][2]), f2b(acc[mf][nf][3]) };
        *(ushort4*)(Vt + (((size_t)b * NH + h) * DKH + d) * SEQ + s2) = pk;
      }
    } else {
      ushort* DST = (z == 0) ? Q : K;
      const float freq = __expf(-(float)(d >> 1) * 0.2878231366242557f);
      #pragma unroll
      for (int mf = 0; mf < 4; ++mf) {
        #pragma unroll
        for (int r = 0; r < 4; ++r) {
          const int m  = m0 + wm + mf * 16 + g * 4 + r;
          const int b  = m >> 11;
          const int s2 = m & (SEQ - 1);
          const float ang = (float)pos[s2] * freq;
          float sn, cs;
          __sincosf(ang, &sn, &cs);
          const float v1 = acc[mf][nf][r];
          const float v2 = __shfl_xor(v1, 1);
          float ov = (d & 1) ? (v2 * sn + v1 * cs)
                             : (v1 * cs - v2 * sn);
          if (z == 0) ov *= 0.1803368801111204f;   // 0.125 * log2(e)
          DST[(((size_t)b * NH + h) * SEQ + s2) * DKH + d] = f2b(ov);
        }
      }
    }
  }
}

// ---------------------------------------------------------------------------
// Wo projection (unchanged).
// ---------------------------------------------------------------------------
__global__ __launch_bounds__(512) void gemm_wo(
    const ushort* __restrict__ A, const ushort* __restrict__ W,
    float* __restrict__ out)
{
  __shared__ __align__(16) char As[2][16384];
  __shared__ __align__(16) char Bs[2][16384];

  const int id  = blockIdx.x;          // 256 blocks
  const int xcd = id & 7;
  const int i   = id >> 3;
  const int mt  = xcd * 4 + (i & 3);
  const int nt  = i >> 2;
  const int m0  = mt * 128;
  const int n0  = nt * 128;

  const int tid  = threadIdx.x;
  const int lane = tid & 63;
  const int w    = tid >> 6;
  const int wm   = (w >> 2) * 64;
  const int wn   = (w & 3) * 32;
  const int li   = lane & 15;
  const int g    = lane >> 4;

  f32x4 acc[4][2] = {};

  auto stage = [&](int t, int buf) {
    const int k0 = t * 64;
    #pragma unroll
    for (int it = 0; it < 2; ++it) {
      const int L  = w * 2048 + it * 1024 + lane * 16;
      const int r  = L >> 7;
      const int sc = ((L >> 4) & 7) ^ (r & 7);
      gll16(A + (size_t)(m0 + r) * DM + k0 + sc * 8, &As[buf][w * 2048 + it * 1024]);
      gll16(W + (size_t)(n0 + r) * DM + k0 + sc * 8, &Bs[buf][w * 2048 + it * 1024]);
    }
  };

  auto compute = [&](int buf) {
    #pragma unroll
    for (int ks = 0; ks < 2; ++ks) {
      bf16x8 af[4], bfr[2];
      #pragma unroll
      for (int mf = 0; mf < 4; ++mf) {
        const int row = wm + mf * 16 + li;
        af[mf] = *(const bf16x8*)(&As[buf][row * 128 + (((ks * 4 + g) ^ (row & 7)) << 4)]);
      }
      #pragma unroll
      for (int nf = 0; nf < 2; ++nf) {
        const int row = wn + nf * 16 + li;
        bfr[nf] = *(const bf16x8*)(&Bs[buf][row * 128 + (((ks * 4 + g) ^ (row & 7)) << 4)]);
      }
      #pragma unroll
      for (int mf = 0; mf < 4; ++mf)
        #pragma unroll
        for (int nf = 0; nf < 2; ++nf)
          acc[mf][nf] = __builtin_amdgcn_mfma_f32_16x16x32_bf16(af[mf], bfr[nf], acc[mf][nf], 0, 0, 0);
    }
  };

  stage(0, 0);
  for (int t = 0; t < 16; ++t) {
    if (t < 15) {
      stage(t + 1, (t + 1) & 1);
      __builtin_amdgcn_sched_barrier(0);
      asm volatile("s_waitcnt vmcnt(4)" ::: "memory");
    } else {
      asm volatile("s_waitcnt vmcnt(0)" ::: "memory");
    }
    __builtin_amdgcn_s_barrier();
    __builtin_amdgcn_sched_barrier(0);
    compute(t & 1);
    __builtin_amdgcn_sched_barrier(0);
    __builtin_amdgcn_s_barrier();
  }

  #pragma unroll
  for (int nf = 0; nf < 2; ++nf)
    #pragma unroll
    for (int mf = 0; mf < 4; ++mf)
      #pragma unroll
      for (int r = 0; r < 4; ++r)
        out[(size_t)(m0 + wm + mf * 16 + g * 4 + r) * DM + n0 + wn + nf * 16 + li] = acc[mf][nf][r];
}

// ---------------------------------------------------------------------------
// Causal flash attention — r13 compute structure + SPLIT-KV x2 inside the
// block. Block = 8 waves (512 thr), one (bh, 64-row q-tile). Waves 0-3
// (half A) process kv-tiles [0,nA); waves 4-7 (half B) process [nA,n)
// CONCURRENTLY into separate single-buffered LDS staging. Trip loop = nA =
// ceil(n/2) <= 16 -> critical path halved vs r13's 32. End merge via LDS
// (lane-aligned, exp2 domain). LDS 48KB -> 3 blocks/CU (24 waves/CU).
// ---------------------------------------------------------------------------
__global__ __launch_bounds__(512) void attn(
    const ushort* __restrict__ Q, const ushort* __restrict__ K,
    const ushort* __restrict__ Vt, ushort* __restrict__ AO)
{
  __shared__ __align__(16) char smem[49152];
  char* KsA = smem;                    // 8KB: half-A K (64 rows x 128B, swz)
  char* VsA = smem + 8192;             // 8KB: half-A V
  char* KsH = smem + 16384;            // 8KB: half-B K
  char* VsH = smem + 24576;            // 8KB: half-B V
  char* Ps  = smem + 32768;            // 16KB: 8 waves x 2KB P-transpose
  float* OmB = (float*)smem;           // merge alias (16KB over KsA+VsA)
  float* mlB = (float*)(smem + 16384); // merge alias (512B over KsH)

  const int tid  = threadIdx.x;
  const int lane = tid & 63;
  const int w    = tid >> 6;           // 0..7
  const int half = w >> 2;             // 0 = kv low half, 1 = kv high half
  const int wl   = w & 3;              // wave within half
  const int li   = lane & 15;
  const int g    = lane >> 4;

  const int bx  = blockIdx.x;          // 1024 blocks
  const int xcd = bx & 7;
  const int idx = bx >> 3;             // 0..127
  const int j   = idx >> 2;            // 0..31
  const int s   = idx & 3;
  const int qb  = (s & 1) ? (31 - j) : j;   // complementary pairing
  const int bh  = s * 8 + xcd;
  const int q0b = qb * 64;
  const int n   = qb + 1;              // kv64 tiles total
  const int nA  = (n + 1) >> 1;        // half-A tiles (= trip count)
  const int nB  = n - nA;              // half-B tiles
  const int myT0 = half ? nA : 0;
  const int myN  = half ? nB : nA;
  const int q0w = q0b + wl * 16;       // wave's 16 q-rows

  const ushort* Qb = Q  + (size_t)bh * SEQ * DKH;
  const ushort* Kb = K  + (size_t)bh * SEQ * DKH;
  const ushort* Vb = Vt + (size_t)bh * DKH * SEQ;
  char* Kc = half ? KsH : KsA;
  char* Vc = half ? VsH : VsA;
  char* Pw = Ps + w * 2048;

  const bf16x8 qf0 = *(const bf16x8*)(Qb + (size_t)(q0w + li) * DKH + g * 8);
  const bf16x8 qf1 = *(const bf16x8*)(Qb + (size_t)(q0w + li) * DKH + 32 + g * 8);

  f32x4 o[4] = {};
  float m_ = -INFINITY, l_ = 0.f;

  auto stage = [&](int kt) {           // stage kv64 tile into this half's bufs
    const int k0 = kt * 64;
    #pragma unroll
    for (int it = 0; it < 2; ++it) {
      const int L  = wl * 2048 + it * 1024 + lane * 16;
      const int r  = L >> 7;
      const int sc = ((L >> 4) & 7) ^ (r & 7);
      gll16(Kb + (size_t)(k0 + r) * DKH + sc * 8, Kc + wl * 2048 + it * 1024);
      gll16(Vb + (size_t)r * SEQ + k0 + sc * 8,   Vc + wl * 2048 + it * 1024);
    }
  };

  auto computeT = [&](int t, bool diag) {
    const int k0 = t * 64;

    f32x4 st[4] = {};
    __builtin_amdgcn_s_setprio(1);
    #pragma unroll
    for (int nf = 0; nf < 4; ++nf) {
      const int row = nf * 16 + li;
      bf16x8 kfa = *(const bf16x8*)(Kc + row * 128 + (((0 + g) ^ (row & 7)) << 4));
      bf16x8 kfb = *(const bf16x8*)(Kc + row * 128 + (((4 + g) ^ (row & 7)) << 4));
      st[nf] = __builtin_amdgcn_mfma_f32_16x16x32_bf16(kfa, qf0, st[nf], 0, 0, 0);
      st[nf] = __builtin_amdgcn_mfma_f32_16x16x32_bf16(kfb, qf1, st[nf], 0, 0, 0);
    }
    __builtin_amdgcn_s_setprio(0);

    if (diag) {
      #pragma unroll
      for (int nf = 0; nf < 4; ++nf)
        #pragma unroll
        for (int r = 0; r < 4; ++r)
          if (k0 + nf * 16 + g * 4 + r > q0w + li) st[nf][r] = -1e30f;
    }

    float mx = fmaxf(fmaxf(fmaxf(st[0][0], st[0][1]), fmaxf(st[0][2], st[0][3])),
                     fmaxf(fmaxf(st[1][0], st[1][1]), fmaxf(st[1][2], st[1][3])));
    mx = fmaxf(mx, fmaxf(fmaxf(fmaxf(st[2][0], st[2][1]), fmaxf(st[2][2], st[2][3])),
                         fmaxf(fmaxf(st[3][0], st[3][1]), fmaxf(st[3][2], st[3][3]))));
    mx = fmaxf(mx, __shfl_xor(mx, 16));
    mx = fmaxf(mx, __shfl_xor(mx, 32));

    const bool rescale = !__all(mx - m_ <= 8.0f);
    float al = 1.0f;
    if (rescale) {
      const float newm = fmaxf(m_, mx);
      al = exp2_fast(m_ - newm);
      m_ = newm;
    }

    float p[4][4];
    float rs = 0.f;
    #pragma unroll
    for (int nf = 0; nf < 4; ++nf)
      #pragma unroll
      for (int r = 0; r < 4; ++r) {
        p[nf][r] = exp2_fast(st[nf][r] - m_);
        rs += p[nf][r];
      }
    rs += __shfl_xor(rs, 16);
    rs += __shfl_xor(rs, 32);

    if (rescale) {
      l_ = l_ * al + rs;
      float alr[4];
      #pragma unroll
      for (int r = 0; r < 4; ++r) alr[r] = __shfl(al, g * 4 + r);
      #pragma unroll
      for (int nf = 0; nf < 4; ++nf)
        #pragma unroll
        for (int r = 0; r < 4; ++r) o[nf][r] *= alr[r];
    } else {
      l_ += rs;
    }

    #pragma unroll
    for (int nf = 0; nf < 4; ++nf) {
      uint2 pv = { cvt_pk(p[nf][0], p[nf][1]), cvt_pk(p[nf][2], p[nf][3]) };
      const int cw = nf * 2 + (g >> 1);
      *(uint2*)(Pw + li * 128 + ((cw ^ (li & 7)) << 4) + ((g & 1) << 3)) = pv;
    }
    bf16x8 pf0 = *(const bf16x8*)(Pw + li * 128 + (((0 + g) ^ (li & 7)) << 4));
    bf16x8 pf1 = *(const bf16x8*)(Pw + li * 128 + (((4 + g) ^ (li & 7)) << 4));

    __builtin_amdgcn_s_setprio(1);
    #pragma unroll
    for (int nf = 0; nf < 4; ++nf) {
      const int row = nf * 16 + li;
      bf16x8 vfa = *(const bf16x8*)(Vc + row * 128 + (((0 + g) ^ (row & 7)) << 4));
      bf16x8 vfb = *(const bf16x8*)(Vc + row * 128 + (((4 + g) ^ (row & 7)) << 4));
      o[nf] = __builtin_amdgcn_mfma_f32_16x16x32_bf16(pf0, vfa, o[nf], 0, 0, 0);
      o[nf] = __builtin_amdgcn_mfma_f32_16x16x32_bf16(pf1, vfb, o[nf], 0, 0, 0);
    }
    __builtin_amdgcn_s_setprio(0);
  };

  // ---- split-KV trip loop: nA <= 16 iterations ----
  for (int t = 0; t < nA; ++t) {
    if (t < myN) stage(myT0 + t);      // wave-uniform condition
    __syncthreads();                   // drains vmcnt; both halves staged
    if (t < myN) computeT(myT0 + t, myT0 + t == n - 1);
    __syncthreads();                   // all reads done before restage
  }

  // ---- merge halves (merge buffers alias the now-idle staging LDS) ----
  if (half) {
    #pragma unroll
    for (int nf = 0; nf < 4; ++nf)
      *(f32x4*)&OmB[(wl * 64 + lane) * 16 + nf * 4] = o[nf];
    mlB[(wl * 16 + li) * 2 + 0] = m_;  // row-indexed (4 lanes same value)
    mlB[(wl * 16 + li) * 2 + 1] = l_;
  }
  __syncthreads();
  if (!half) {
    const float mB = mlB[(wl * 16 + li) * 2 + 0];
    const float lB = mlB[(wl * 16 + li) * 2 + 1];
    const float mN = fmaxf(m_, mB);
    const float a  = exp2_fast(m_ - mN);
    const float bs = exp2_fast(mB - mN);   // 2^(-inf) = 0 when nB == 0
    const float lN = l_ * a + lB * bs;
    const float inv = 1.0f / lN;

    float ar[4], br[4], ir[4];
    #pragma unroll
    for (int r = 0; r < 4; ++r) {
      ar[r] = __shfl(a,   g * 4 + r);
      br[r] = __shfl(bs,  g * 4 + r);
      ir[r] = __shfl(inv, g * 4 + r);
    }

    const int b = bh >> 4, h = bh & 15;
    #pragma unroll
    for (int nf = 0; nf < 4; ++nf) {
      const f32x4 ob = *(const f32x4*)&OmB[(wl * 64 + lane) * 16 + nf * 4];
      #pragma unroll
      for (int r = 0; r < 4; ++r) {
        const int q = q0w + g * 4 + r;
        const float v = (o[nf][r] * ar[r] + ob[r] * br[r]) * ir[r];
        AO[((size_t)b * SEQ + q) * DM + h * DKH + nf * 16 + li] = f2b(v);
      }
    }
  }
}

// ---------------------------------------------------------------------------
extern "C" void kernel_launch(void* const* d_in, const int* in_sizes, int n_in,
                              void* d_out, int out_size, void* d_ws, size_t ws_size,
                              hipStream_t stream)
{
  const float* x   = (const float*)d_in[0];
  const int*   pos = (const int*)  d_in[1];
  const float* Wq  = (const float*)d_in[2];
  const float* Wk  = (const float*)d_in[3];
  const float* Wv  = (const float*)d_in[4];
  const float* Wo  = (const float*)d_in[5];
  float* out = (float*)d_out;

  ushort* ws  = (ushort*)d_ws;
  ushort* xb  = ws;                    // 4M
  ushort* wqb = xb  + 4194304;         // 1M each
  ushort* wkb = wqb + 1048576;
  ushort* wvb = wkb + 1048576;
  ushort* wob = wvb + 1048576;
  ushort* Qb  = wob + 1048576;         // 4M each
  ushort* Kb  = Qb  + 4194304;
  ushort* Vtb = Kb  + 4194304;
  ushort* AOb = Vtb + 4194304;

  cvt_all<<<8192, 256, 0, stream>>>(x, Wq, Wk, Wv, Wo, xb, wqb, wkb, wvb, wob);
  gemm_qkv<<<768, 512, 0, stream>>>(xb, wqb, wkb, wvb, Qb, Kb, Vtb, pos);
  attn<<<1024, 512, 0, stream>>>(Qb, Kb, Vtb, AOb);
  gemm_wo<<<256, 512, 0, stream>>>(AOb, wob, out);
}